// Round 11
// baseline (372.946 us; speedup 1.0000x reference)
//
#include <hip/hip_runtime.h>
#include <hip/hip_bf16.h>

// Problem constants: B,T,V,E,U = 256,512,20000,128,128
#define BB 256
#define TT 512
#define VV 20000
#define EE 128
#define UU 128
#define G4 512   // 4*U gate width

typedef _Float16 h2 __attribute__((ext_vector_type(2)));

__device__ __forceinline__ float sigmoid_f(float x) {
    float e = __expf(-x);
    return __builtin_amdgcn_rcpf(1.0f + e);
}
__device__ __forceinline__ float tanh_f(float x) {
    float e = __expf(2.0f * x);
    return 1.0f - 2.0f * __builtin_amdgcn_rcpf(e + 1.0f);
}

// ---- guaranteed-native packed f16 math (clang promotes C++ f16 vectors!) ----
__device__ __forceinline__ h2 pk_fma(h2 a, h2 b, h2 c) {
    int d, ia = __builtin_bit_cast(int, a), ib = __builtin_bit_cast(int, b),
        ic = __builtin_bit_cast(int, c);
    asm("v_pk_fma_f16 %0, %1, %2, %3" : "=v"(d) : "v"(ia), "v"(ib), "v"(ic));
    return __builtin_bit_cast(h2, d);
}
__device__ __forceinline__ h2 pk_add(h2 a, h2 b) {
    int d, ia = __builtin_bit_cast(int, a), ib = __builtin_bit_cast(int, b);
    asm("v_pk_add_f16 %0, %1, %2" : "=v"(d) : "v"(ia), "v"(ib));
    return __builtin_bit_cast(h2, d);
}

// DPP quad_perm broadcasts (quads = lane groups 4k..4k+3)
__device__ __forceinline__ float dpp_f(float v, int pat) {
    switch (pat) {
        case 0x00: return __int_as_float(__builtin_amdgcn_mov_dpp(__float_as_int(v), 0x00, 0xF, 0xF, true));
        case 0x55: return __int_as_float(__builtin_amdgcn_mov_dpp(__float_as_int(v), 0x55, 0xF, 0xF, true));
        case 0xAA: return __int_as_float(__builtin_amdgcn_mov_dpp(__float_as_int(v), 0xAA, 0xF, 0xF, true));
        default:   return __int_as_float(__builtin_amdgcn_mov_dpp(__float_as_int(v), 0xFF, 0xF, 0xF, true));
    }
}

// ---------------------------------------------------------------------------
// Phase 1: projected-token table in GATE-MINOR layout:
//   P2[v][u][g] = sum_e emb[v][e]*K[e][g*128+u] + bias[g*128+u]
// ---------------------------------------------------------------------------
__global__ __launch_bounds__(512, 2) void proj_kernel(
    const float* __restrict__ emb, const float* __restrict__ wk,
    const float* __restrict__ bias, float* __restrict__ P2) {
    const int tid = threadIdx.x;
    const int g   = tid & 3;
    const int u   = tid >> 2;
    const int col = g * 128 + u;
    const int v0  = blockIdx.x * 16;

    __shared__ float elds[16 * EE];
    ((float4*)elds)[tid] = ((const float4*)(emb + (size_t)v0 * EE))[tid];
    __syncthreads();

    float bcol = bias[col];
    float acc[16];
#pragma unroll
    for (int r = 0; r < 16; ++r) acc[r] = bcol;

    const float4* elds4 = (const float4*)elds;
    for (int e0 = 0; e0 < EE; e0 += 4) {
        float k0 = wk[(e0 + 0) * G4 + col];
        float k1 = wk[(e0 + 1) * G4 + col];
        float k2 = wk[(e0 + 2) * G4 + col];
        float k3 = wk[(e0 + 3) * G4 + col];
#pragma unroll
        for (int r = 0; r < 16; ++r) {
            float4 ev = elds4[r * 32 + (e0 >> 2)];
            acc[r] = fmaf(ev.x, k0, acc[r]);
            acc[r] = fmaf(ev.y, k1, acc[r]);
            acc[r] = fmaf(ev.z, k2, acc[r]);
            acc[r] = fmaf(ev.w, k3, acc[r]);
        }
    }
#pragma unroll
    for (int r = 0; r < 16; ++r)
        P2[(size_t)(v0 + r) * G4 + tid] = acc[r];   // [v][u][g], coalesced
}

// ---------------------------------------------------------------------------
// Phase 2: sequential LSTM, full-column VALU formulation.
// Lane (u=tid>>2, q=tid&3) computes the COMPLETE 128-dim dot for gate q of
// unit u: 64 resident f16x2 weight VGPRs, 64 inline-asm v_pk_fma_f16
// (2 MAC/instr, native — C++ f16 vector math was being promoted to f32,
// the R9/R10 2x overhead), 7-pk_add tree, NO cross-lane butterfly. h is
// read as 16 wave-uniform ds_read_b128 broadcasts (conflict-free). Each
// lane activates only its own gate (2 trans, tanh identity for q==2); the
// 4 activations of a unit exchange via 4 quad-perm DPP broadcasts; c/h
// update redundant x4 per quad. waves_per_eu(2,2) pins the 256-VGPR budget
// (proven residency in R9/R10). Depth-2 static P prefetch from gate-minor
// P2 (scalar coalesced loads, in flight across 2 barriers); tokens in LDS;
// lgkmcnt(0)-only drain + raw s_barrier per step.
// ---------------------------------------------------------------------------
__global__ __launch_bounds__(512) __attribute__((amdgpu_waves_per_eu(2, 2)))
void lstm_kernel(
    const int* __restrict__ tokens, const float* __restrict__ rk,
    const float* __restrict__ P2, const float* __restrict__ dense_w,
    const float* __restrict__ dense_b, float* __restrict__ out) {
    const int tid = threadIdx.x;
    const int u   = tid >> 2;       // unit 0..127
    const int q   = tid & 3;        // gate 0=i,1=f,2=g,3=o
    const int b   = blockIdx.x;

    __shared__ __align__(16) _Float16 hh[2][UU];   // double-buffered h (f16)
    __shared__ int   tokLDS[TT + 4];
    __shared__ float red[8];

    // ---- weights: wgt[p] = f16x2( rk[2p][q*128+u], rk[2p+1][q*128+u] ) ----
    h2 wgt[64];
    {
        const int c = q * 128 + u;
#pragma unroll
        for (int p = 0; p < 64; ++p) {
            h2 hw;
            hw.x = (_Float16)rk[(size_t)(2 * p + 0) * G4 + c];
            hw.y = (_Float16)rk[(size_t)(2 * p + 1) * G4 + c];
            wgt[p] = hw;
        }
    }

    const int* trow = tokens + (size_t)b * TT;
    tokLDS[tid] = trow[tid];
    if (tid < 4) tokLDS[TT + tid] = trow[TT - 1];
    if (tid < UU) hh[0][tid] = (_Float16)0.f;      // h0 = 0

    const float* Pcol = P2 + (size_t)(4 * u + q);  // lane's dword in a P2 row
    float c_state = 0.f, hv = 0.f;
    float pf0 = Pcol[(size_t)trow[0] * G4];
    float pf1 = Pcol[(size_t)trow[1] * G4];
    __syncthreads();

    const h2 zzero = {(_Float16)0.f, (_Float16)0.f};

#define LSTEP(PAR, PF)                                                        \
    {                                                                         \
        int vtok = tokLDS[t + (PAR) + 2];                                     \
        float pcur = (PF);                       /* 2-step-old load */        \
        (PF) = Pcol[(size_t)vtok * G4];          /* in flight ~2 steps */     \
        /* h: 16 wave-uniform b128 broadcasts -> 64 h2 */                     \
        const int4* hp = (const int4*)&hh[PAR][0];                            \
        int4 hw_[16];                                                         \
        _Pragma("unroll")                                                     \
        for (int r = 0; r < 16; ++r) hw_[r] = hp[r];                          \
        /* 8 independent chains x 8 deep of native pk_fma */                  \
        h2 acc[8];                                                            \
        _Pragma("unroll")                                                     \
        for (int c = 0; c < 8; ++c) acc[c] = zzero;                           \
        _Pragma("unroll")                                                     \
        for (int i = 0; i < 8; ++i) {                                         \
            _Pragma("unroll")                                                 \
            for (int c = 0; c < 8; ++c) {                                     \
                int pi = i * 8 + c;                                           \
                h2 hval = __builtin_bit_cast(h2, (&hw_[0].x)[pi * 4 / 4]);    \
                acc[c] = pk_fma(hval, wgt[pi], acc[c]);                       \
            }                                                                 \
        }                                                                     \
        /* 7-add tree -> packed pair -> scalar z */                           \
        h2 s01 = pk_add(acc[0], acc[1]), s23 = pk_add(acc[2], acc[3]);        \
        h2 s45 = pk_add(acc[4], acc[5]), s67 = pk_add(acc[6], acc[7]);        \
        h2 s03 = pk_add(s01, s23), s47 = pk_add(s45, s67);                    \
        h2 sAll = pk_add(s03, s47);                                           \
        float zq = (float)sAll.x + (float)sAll.y + pcur;                      \
        /* own-gate activation (2 trans; tanh identity for q==2) */           \
        float xs = (q == 2) ? zq + zq : zq;                                   \
        float sg = sigmoid_f(xs);                                             \
        float av = (q == 2) ? fmaf(2.f, sg, -1.f) : sg;                       \
        /* i,f,g,o via quad broadcasts */                                     \
        float ai  = dpp_f(av, 0x00);                                          \
        float af_ = dpp_f(av, 0x55);                                          \
        float ag  = dpp_f(av, 0xAA);                                          \
        float ao  = dpp_f(av, 0xFF);                                          \
        c_state = fmaf(af_, c_state, ai * ag);                                \
        hv      = ao * tanh_f(c_state);                                       \
        if (q == 0) hh[(PAR) ^ 1][u] = (_Float16)hv;                          \
        asm volatile("s_waitcnt lgkmcnt(0)" ::: "memory");                    \
        __builtin_amdgcn_s_barrier();                                         \
    }

    for (int t = 0; t < TT; t += 2) {
        LSTEP(0, pf0)
        LSTEP(1, pf1)
    }
#undef LSTEP

    // --- dense sigmoid head: out[b] = sigmoid(h @ w + b) ---
    float val = (q == 0) ? hv * dense_w[u] : 0.f;
#pragma unroll
    for (int off = 32; off > 0; off >>= 1) val += __shfl_xor(val, off, 64);
    if ((tid & 63) == 0) red[tid >> 6] = val;
    __syncthreads();
    if (tid == 0) {
        float s = dense_b[0];
#pragma unroll
        for (int i = 0; i < 8; ++i) s += red[i];
        out[b] = sigmoid_f(s);
    }
}

extern "C" void kernel_launch(void* const* d_in, const int* in_sizes, int n_in,
                              void* d_out, int out_size, void* d_ws, size_t ws_size,
                              hipStream_t stream) {
    const int*   tokens = (const int*)  d_in[0];
    const float* emb    = (const float*)d_in[1];
    const float* wk     = (const float*)d_in[2];
    const float* rk     = (const float*)d_in[3];
    const float* bias   = (const float*)d_in[4];
    const float* dw     = (const float*)d_in[5];
    const float* db     = (const float*)d_in[6];
    float* out = (float*)d_out;
    float* P2  = (float*)d_ws;     // 20000*512*4 = 40.96 MB scratch

    proj_kernel<<<VV / 16, 512, 0, stream>>>(emb, wk, bias, P2);
    lstm_kernel<<<BB, 512, 0, stream>>>(tokens, rk, P2, dw, db, out);
}

// Round 12
// 364.552 us; speedup vs baseline: 1.0230x; 1.0230x over previous
//
#include <hip/hip_runtime.h>
#include <hip/hip_bf16.h>

// Problem constants: B,T,V,E,U = 256,512,20000,128,128
#define BB 256
#define TT 512
#define VV 20000
#define EE 128
#define UU 128
#define G4 512   // 4*U gate width

typedef _Float16 h2 __attribute__((ext_vector_type(2)));

__device__ __forceinline__ float sigmoid_f(float x) {
    float e = __expf(-x);
    return __builtin_amdgcn_rcpf(1.0f + e);
}
__device__ __forceinline__ float tanh_f(float x) {
    float e = __expf(2.0f * x);
    return 1.0f - 2.0f * __builtin_amdgcn_rcpf(e + 1.0f);
}

// ---- guaranteed-native packed f16 math (clang promotes C++ f16 vectors) ----
__device__ __forceinline__ h2 pk_fma(h2 a, h2 b, h2 c) {
    int d, ia = __builtin_bit_cast(int, a), ib = __builtin_bit_cast(int, b),
        ic = __builtin_bit_cast(int, c);
    asm("v_pk_fma_f16 %0, %1, %2, %3" : "=v"(d) : "v"(ia), "v"(ib), "v"(ic));
    return __builtin_bit_cast(h2, d);
}
__device__ __forceinline__ h2 pk_add(h2 a, h2 b) {
    int d, ia = __builtin_bit_cast(int, a), ib = __builtin_bit_cast(int, b);
    asm("v_pk_add_f16 %0, %1, %2" : "=v"(d) : "v"(ia), "v"(ib));
    return __builtin_bit_cast(h2, d);
}

// DPP quad_perm (quads = lane groups 4k..4k+3); pat must be a literal case
__device__ __forceinline__ int dpp_i(int v, int pat) {
    switch (pat) {
        case 0xB1: return __builtin_amdgcn_mov_dpp(v, 0xB1, 0xF, 0xF, true);
        case 0x4E: return __builtin_amdgcn_mov_dpp(v, 0x4E, 0xF, 0xF, true);
        case 0x00: return __builtin_amdgcn_mov_dpp(v, 0x00, 0xF, 0xF, true);
        case 0x55: return __builtin_amdgcn_mov_dpp(v, 0x55, 0xF, 0xF, true);
        case 0xAA: return __builtin_amdgcn_mov_dpp(v, 0xAA, 0xF, 0xF, true);
        default:   return __builtin_amdgcn_mov_dpp(v, 0xFF, 0xF, 0xF, true);
    }
}
__device__ __forceinline__ float dpp_f(float v, int pat) {
    return __int_as_float(dpp_i(__float_as_int(v), pat));
}
__device__ __forceinline__ h2 pk_add_dpp(h2 s, int pat) {
    int m = dpp_i(__builtin_bit_cast(int, s), pat);
    return pk_add(s, __builtin_bit_cast(h2, m));
}

// ---------------------------------------------------------------------------
// Phase 1: projected-token table in GATE-MINOR layout:
//   P2[v][u][g] = sum_e emb[v][e]*K[e][g*128+u] + bias[g*128+u]
// ---------------------------------------------------------------------------
__global__ __launch_bounds__(512, 2) void proj_kernel(
    const float* __restrict__ emb, const float* __restrict__ wk,
    const float* __restrict__ bias, float* __restrict__ P2) {
    const int tid = threadIdx.x;
    const int g   = tid & 3;
    const int u   = tid >> 2;
    const int col = g * 128 + u;
    const int v0  = blockIdx.x * 16;

    __shared__ float elds[16 * EE];
    ((float4*)elds)[tid] = ((const float4*)(emb + (size_t)v0 * EE))[tid];
    __syncthreads();

    float bcol = bias[col];
    float acc[16];
#pragma unroll
    for (int r = 0; r < 16; ++r) acc[r] = bcol;

    const float4* elds4 = (const float4*)elds;
    for (int e0 = 0; e0 < EE; e0 += 4) {
        float k0 = wk[(e0 + 0) * G4 + col];
        float k1 = wk[(e0 + 1) * G4 + col];
        float k2 = wk[(e0 + 2) * G4 + col];
        float k3 = wk[(e0 + 3) * G4 + col];
#pragma unroll
        for (int r = 0; r < 16; ++r) {
            float4 ev = elds4[r * 32 + (e0 >> 2)];
            acc[r] = fmaf(ev.x, k0, acc[r]);
            acc[r] = fmaf(ev.y, k1, acc[r]);
            acc[r] = fmaf(ev.z, k2, acc[r]);
            acc[r] = fmaf(ev.w, k3, acc[r]);
        }
    }
#pragma unroll
    for (int r = 0; r < 16; ++r)
        P2[(size_t)(v0 + r) * G4 + tid] = acc[r];   // [v][u][g], coalesced
}

// ---------------------------------------------------------------------------
// Phase 2: sequential LSTM on the VALU. Geometry of R10 (lane (u,q): 32-dim
// h slice x 4 gate columns of unit u -> only 4 ds_read_b128/lane/step; the
// R11 full-column version was LDS-pipe-bound at 16/lane) + native packed
// math of R11 (inline-asm v_pk_fma_f16/v_pk_add_f16 — C++ f16-vector ops
// get promoted to f32 chains, the R9/R10 2x instruction bloat).
// 64 resident f16x2 weight VGPRs (waves_per_eu(2,2), proven 88-reg fit),
// 8 pk_fma chains, packed quad butterfly (mov_dpp + asm pk_add), own-gate
// activation (2 trans), 4 quad DPP broadcasts, redundant c/h per quad.
// Depth-2 static P prefetch from gate-minor P2; tokens in LDS;
// lgkmcnt(0)-only drain + raw s_barrier per step.
// ---------------------------------------------------------------------------
__global__ __launch_bounds__(512) __attribute__((amdgpu_waves_per_eu(2, 2)))
void lstm_kernel(
    const int* __restrict__ tokens, const float* __restrict__ rk,
    const float* __restrict__ P2, const float* __restrict__ dense_w,
    const float* __restrict__ dense_b, float* __restrict__ out) {
    const int tid = threadIdx.x;
    const int u   = tid >> 2;       // unit 0..127
    const int q   = tid & 3;        // slice & gate 0..3
    const int b   = blockIdx.x;

    __shared__ __align__(16) _Float16 hh[2][UU];   // double-buffered h (f16)
    __shared__ int   tokLDS[TT + 4];
    __shared__ float red[8];

    // ---- weights: wgt[g][p] = f16x2( rk[32q+2p][g*128+u], rk[32q+2p+1][..] )
    h2 wgt[4][16];
    const float* rkb = rk + (size_t)(32 * q) * G4;
#pragma unroll
    for (int g = 0; g < 4; ++g) {
        const int c = g * 128 + u;
#pragma unroll
        for (int p = 0; p < 16; ++p) {
            h2 hw;
            hw.x = (_Float16)rkb[(2 * p + 0) * G4 + c];
            hw.y = (_Float16)rkb[(2 * p + 1) * G4 + c];
            wgt[g][p] = hw;
        }
    }

    const int* trow = tokens + (size_t)b * TT;
    tokLDS[tid] = trow[tid];
    if (tid < 4) tokLDS[TT + tid] = trow[TT - 1];
    if (tid < UU) hh[0][tid] = (_Float16)0.f;      // h0 = 0

    const float* Pcol = P2 + (size_t)(4 * u + q);  // lane's dword in a P2 row
    float c_state = 0.f, hv = 0.f;
    float pf0 = Pcol[(size_t)trow[0] * G4];
    float pf1 = Pcol[(size_t)trow[1] * G4];
    __syncthreads();

    const h2 zzero = {(_Float16)0.f, (_Float16)0.f};

#define LSTEP(PAR, PF)                                                        \
    {                                                                         \
        int vtok = tokLDS[t + (PAR) + 2];                                     \
        float pcur = (PF);                       /* 2-step-old load */        \
        (PF) = Pcol[(size_t)vtok * G4];          /* in flight ~2 steps */     \
        /* this lane's 32-dim h slice: 4 x ds_read_b128 */                    \
        const int4* hrow = (const int4*)&hh[PAR][32 * q];                     \
        int4 hA = hrow[0], hB = hrow[1], hC = hrow[2], hD = hrow[3];          \
        h2 hr[16];                                                            \
        hr[0]  = __builtin_bit_cast(h2, hA.x);                                \
        hr[1]  = __builtin_bit_cast(h2, hA.y);                                \
        hr[2]  = __builtin_bit_cast(h2, hA.z);                                \
        hr[3]  = __builtin_bit_cast(h2, hA.w);                                \
        hr[4]  = __builtin_bit_cast(h2, hB.x);                                \
        hr[5]  = __builtin_bit_cast(h2, hB.y);                                \
        hr[6]  = __builtin_bit_cast(h2, hB.z);                                \
        hr[7]  = __builtin_bit_cast(h2, hB.w);                                \
        hr[8]  = __builtin_bit_cast(h2, hC.x);                                \
        hr[9]  = __builtin_bit_cast(h2, hC.y);                                \
        hr[10] = __builtin_bit_cast(h2, hC.z);                                \
        hr[11] = __builtin_bit_cast(h2, hC.w);                                \
        hr[12] = __builtin_bit_cast(h2, hD.x);                                \
        hr[13] = __builtin_bit_cast(h2, hD.y);                                \
        hr[14] = __builtin_bit_cast(h2, hD.z);                                \
        hr[15] = __builtin_bit_cast(h2, hD.w);                                \
        /* 8 native pk_fma chains (2 per gate, depth 8) */                    \
        h2 a0[4], a1[4];                                                      \
        _Pragma("unroll")                                                     \
        for (int g = 0; g < 4; ++g) { a0[g] = zzero; a1[g] = zzero; }         \
        _Pragma("unroll")                                                     \
        for (int p = 0; p < 16; p += 2) {                                     \
            _Pragma("unroll")                                                 \
            for (int g = 0; g < 4; ++g) {                                     \
                a0[g] = pk_fma(hr[p],     wgt[g][p],     a0[g]);              \
                a1[g] = pk_fma(hr[p + 1], wgt[g][p + 1], a1[g]);              \
            }                                                                 \
        }                                                                     \
        /* packed quad butterfly (all asm pk_add + mov_dpp) */                \
        h2 s0 = pk_add(a0[0], a1[0]), s1 = pk_add(a0[1], a1[1]);              \
        h2 s2 = pk_add(a0[2], a1[2]), s3 = pk_add(a0[3], a1[3]);              \
        s0 = pk_add_dpp(s0, 0xB1); s0 = pk_add_dpp(s0, 0x4E);                 \
        s1 = pk_add_dpp(s1, 0xB1); s1 = pk_add_dpp(s1, 0x4E);                 \
        s2 = pk_add_dpp(s2, 0xB1); s2 = pk_add_dpp(s2, 0x4E);                 \
        s3 = pk_add_dpp(s3, 0xB1); s3 = pk_add_dpp(s3, 0x4E);                 \
        /* lane q horizontalizes + activates only gate q */                   \
        int ilo = (q & 1) ? __builtin_bit_cast(int, s1)                       \
                          : __builtin_bit_cast(int, s0);                      \
        int ihi = (q & 1) ? __builtin_bit_cast(int, s3)                       \
                          : __builtin_bit_cast(int, s2);                      \
        h2 own  = __builtin_bit_cast(h2, (q & 2) ? ihi : ilo);                \
        float zq = (float)own.x + (float)own.y + pcur;                        \
        float xs = (q == 2) ? zq + zq : zq;                                   \
        float sg = sigmoid_f(xs);                                             \
        float av = (q == 2) ? fmaf(2.f, sg, -1.f) : sg;                       \
        /* i,f,g,o via quad broadcasts */                                     \
        float ai  = dpp_f(av, 0x00);                                          \
        float af_ = dpp_f(av, 0x55);                                          \
        float ag  = dpp_f(av, 0xAA);                                          \
        float ao  = dpp_f(av, 0xFF);                                          \
        c_state = fmaf(af_, c_state, ai * ag);                                \
        hv      = ao * tanh_f(c_state);                                       \
        if (q == 0) hh[(PAR) ^ 1][u] = (_Float16)hv;                          \
        asm volatile("s_waitcnt lgkmcnt(0)" ::: "memory");                    \
        __builtin_amdgcn_s_barrier();                                         \
    }

    for (int t = 0; t < TT; t += 2) {
        LSTEP(0, pf0)
        LSTEP(1, pf1)
    }
#undef LSTEP

    // --- dense sigmoid head: out[b] = sigmoid(h @ w + b) ---
    float val = (q == 0) ? hv * dense_w[u] : 0.f;
#pragma unroll
    for (int off = 32; off > 0; off >>= 1) val += __shfl_xor(val, off, 64);
    if ((tid & 63) == 0) red[tid >> 6] = val;
    __syncthreads();
    if (tid == 0) {
        float s = dense_b[0];
#pragma unroll
        for (int i = 0; i < 8; ++i) s += red[i];
        out[b] = sigmoid_f(s);
    }
}

extern "C" void kernel_launch(void* const* d_in, const int* in_sizes, int n_in,
                              void* d_out, int out_size, void* d_ws, size_t ws_size,
                              hipStream_t stream) {
    const int*   tokens = (const int*)  d_in[0];
    const float* emb    = (const float*)d_in[1];
    const float* wk     = (const float*)d_in[2];
    const float* rk     = (const float*)d_in[3];
    const float* bias   = (const float*)d_in[4];
    const float* dw     = (const float*)d_in[5];
    const float* db     = (const float*)d_in[6];
    float* out = (float*)d_out;
    float* P2  = (float*)d_ws;     // 20000*512*4 = 40.96 MB scratch

    proj_kernel<<<VV / 16, 512, 0, stream>>>(emb, wk, bias, P2);
    lstm_kernel<<<BB, 512, 0, stream>>>(tokens, rk, P2, dw, db, out);
}

// Round 13
// 303.138 us; speedup vs baseline: 1.2303x; 1.2026x over previous
//
#include <hip/hip_runtime.h>
#include <hip/hip_bf16.h>

// Problem constants: B,T,V,E,U = 256,512,20000,128,128
#define BB 256
#define TT 512
#define VV 20000
#define EE 128
#define UU 128
#define G4 512   // 4*U gate width

typedef _Float16 f16x8 __attribute__((ext_vector_type(8)));
typedef float    f32x4 __attribute__((ext_vector_type(4)));

__device__ __forceinline__ float sigmoid_f(float x) {
    float e = __expf(-x);
    return __builtin_amdgcn_rcpf(1.0f + e);
}
__device__ __forceinline__ float tanh_f(float x) {
    float e = __expf(2.0f * x);
    return 1.0f - 2.0f * __builtin_amdgcn_rcpf(e + 1.0f);
}

// ---------------------------------------------------------------------------
// Phase 1: projected-token table  P[v][g] = sum_e emb[v][e]*K[e][g] + bias[g]
// (column-major gate layout, matching the lstm kernel's per-lane scalar gather)
// ---------------------------------------------------------------------------
__global__ __launch_bounds__(512, 2) void proj_kernel(
    const float* __restrict__ emb, const float* __restrict__ wk,
    const float* __restrict__ bias, float* __restrict__ P) {
    const int col = threadIdx.x;
    const int v0  = blockIdx.x * 16;

    __shared__ float elds[16 * EE];
    ((float4*)elds)[col] = ((const float4*)(emb + (size_t)v0 * EE))[col];
    __syncthreads();

    float bcol = bias[col];
    float acc[16];
#pragma unroll
    for (int r = 0; r < 16; ++r) acc[r] = bcol;

    const float4* elds4 = (const float4*)elds;
    for (int e0 = 0; e0 < EE; e0 += 4) {
        float k0 = wk[(e0 + 0) * G4 + col];
        float k1 = wk[(e0 + 1) * G4 + col];
        float k2 = wk[(e0 + 2) * G4 + col];
        float k3 = wk[(e0 + 3) * G4 + col];
#pragma unroll
        for (int r = 0; r < 16; ++r) {
            float4 ev = elds4[r * 32 + (e0 >> 2)];
            acc[r] = fmaf(ev.x, k0, acc[r]);
            acc[r] = fmaf(ev.y, k1, acc[r]);
            acc[r] = fmaf(ev.z, k2, acc[r]);
            acc[r] = fmaf(ev.w, k3, acc[r]);
        }
    }
#pragma unroll
    for (int r = 0; r < 16; ++r)
        P[(size_t)(v0 + r) * G4 + col] = acc[r];
}

// ---------------------------------------------------------------------------
// Phase 2: sequential LSTM via MFMA — restoration of the measured-best
// structure (R5msg / 267 us) + serial-chain trims:
//  * 16x16x32 MFMA, wave w owns gate-cols {i,f,g,o} x units [16w,16w+16),
//    B-fragments resident (loaded once); A = h broadcast slices from LDS.
//  * 2-deep accumulator chains (accA/accB) halve dependent-MFMA latency.
//  * gate-specialized activation: lane 16g+j activates only gate g (2 trans);
//    i,f,g,o gathered to kq==0 lanes via 3 shuffles, with the o-shuffle
//    issued BEFORE the tanh(c) chain so its latency hides under it.
//  * depth-4 static P prefetch (pf[4], loop-carried SSA, counted vmcnt);
//    tokens staged in LDS, PADDED by 8 (no per-step clamp).
//  * lgkmcnt(0)-only drain + raw s_barrier: P loads cross the barrier.
// ---------------------------------------------------------------------------
__global__ __launch_bounds__(512, 2) void lstm_kernel(
    const int* __restrict__ tokens, const float* __restrict__ rk,
    const float* __restrict__ P, const float* __restrict__ dense_w,
    const float* __restrict__ dense_b, float* __restrict__ out) {
    const int tid = threadIdx.x;
    const int w   = tid >> 6;       // wave 0..7
    const int l   = tid & 63;       // lane
    const int j   = l & 15;         // unit index within the wave's 16
    const int kq  = l >> 4;         // lane's gate (0=i,1=f,2=g,3=o)
    const int b   = blockIdx.x;
    const int ucol = 16 * w + j;    // unit column

    __shared__ __align__(16) _Float16 hbuf[2][UU];  // double-buffered h
    __shared__ int   tokLDS[TT + 8];                // padded token row
    __shared__ float red[8];

    // ---- B-fragments: bf[kt][g][i] = rk[32kt+8kq+i][g*128 + ucol] (f16) ----
    f16x8 bf[4][4];
#pragma unroll
    for (int kt = 0; kt < 4; ++kt) {
#pragma unroll
        for (int g = 0; g < 4; ++g) {
            f16x8 v;
#pragma unroll
            for (int i = 0; i < 8; ++i) {
                v[i] = (_Float16)rk[(size_t)(32 * kt + 8 * kq + i) * G4
                                    + g * 128 + ucol];
            }
            bf[kt][g] = v;
        }
    }

    const int* trow = tokens + (size_t)b * TT;
    tokLDS[tid] = trow[tid];
    if (tid < 8) tokLDS[TT + tid] = trow[TT - 1];   // pad: no clamp in loop
    if (tid < UU) hbuf[0][tid] = (_Float16)0.f;     // h0 = 0
    float c_state = 0.f, hv = 0.f;

    const float* Pcol = P + (size_t)kq * 128 + ucol;  // this lane's P column
    // depth-4 prologue: P for t = 0..3
    float pf[4];
#pragma unroll
    for (int s = 0; s < 4; ++s) pf[s] = Pcol[(size_t)trow[s] * G4];
    __syncthreads();

    const f32x4 cz = {0.f, 0.f, 0.f, 0.f};

    for (int t = 0; t < TT; t += 4) {
#pragma unroll
        for (int s = 0; s < 4; ++s) {
            // --- token for t+s+4 (LDS, padded) ---
            int vtok = tokLDS[t + s + 4];

            // --- A-fragments: h broadcast slices from LDS ---
            f16x8 af[4];
#pragma unroll
            for (int kt = 0; kt < 4; ++kt)
                af[kt] = *(const f16x8*)&hbuf[s & 1][32 * kt + 8 * kq];

            // --- issue P prefetch early (flies over the MFMAs) ---
            float pnew = Pcol[(size_t)vtok * G4];

            // --- z = h @ R : 8 independent chains (depth 2), 16 MFMA ---
            f32x4 accA[4], accB[4];
#pragma unroll
            for (int g = 0; g < 4; ++g) {
                accA[g] = __builtin_amdgcn_mfma_f32_16x16x32_f16(af[0], bf[0][g], cz, 0, 0, 0);
                accB[g] = __builtin_amdgcn_mfma_f32_16x16x32_f16(af[2], bf[2][g], cz, 0, 0, 0);
            }
#pragma unroll
            for (int g = 0; g < 4; ++g) {
                accA[g] = __builtin_amdgcn_mfma_f32_16x16x32_f16(af[1], bf[1][g], accA[g], 0, 0, 0);
                accB[g] = __builtin_amdgcn_mfma_f32_16x16x32_f16(af[3], bf[3][g], accB[g], 0, 0, 0);
            }

            // --- this lane's gate value: z[kq][unit j] + P ---
            float z0 = accA[0][0] + accB[0][0];
            float z1 = accA[1][0] + accB[1][0];
            float z2 = accA[2][0] + accB[2][0];
            float z3 = accA[3][0] + accB[3][0];
            float zl = (kq & 2) ? ((kq & 1) ? z3 : z2) : ((kq & 1) ? z1 : z0);
            zl += pf[s];

            // --- one activation per lane (tanh identity for kq==2) ---
            float xs = (kq == 2) ? zl + zl : zl;
            float sg = sigmoid_f(xs);
            float a  = (kq == 2) ? fmaf(2.f, sg, -1.f) : sg;

            // --- gather i,f,g,o of unit j to the kq==0 lanes ---
            // (o-shuffle issued before the tanh(c) chain: latency hidden)
            float fa = __shfl(a, j + 16, 64);
            float ga = __shfl(a, j + 32, 64);
            float oa = __shfl(a, j + 48, 64);

            // --- state update (valid on kq==0 lanes) ---
            c_state  = fmaf(fa, c_state, a * ga);
            float tc = tanh_f(c_state);
            hv       = oa * tc;

            if (kq == 0) hbuf[(s + 1) & 1][ucol] = (_Float16)hv;  // publish h
            pf[s] = pnew;

            // LDS-only drain + raw barrier: P loads survive across steps
            asm volatile("s_waitcnt lgkmcnt(0)" ::: "memory");
            __builtin_amdgcn_s_barrier();
        }
    }

    // --- dense sigmoid head: out[b] = sigmoid(h @ w + b) ---
    float val = (kq == 0) ? hv * dense_w[ucol] : 0.f;
#pragma unroll
    for (int off = 32; off > 0; off >>= 1) val += __shfl_xor(val, off, 64);
    if (l == 0) red[w] = val;
    __syncthreads();
    if (tid == 0) {
        float sum = dense_b[0];
#pragma unroll
        for (int i = 0; i < 8; ++i) sum += red[i];
        out[b] = sigmoid_f(sum);
    }
}

extern "C" void kernel_launch(void* const* d_in, const int* in_sizes, int n_in,
                              void* d_out, int out_size, void* d_ws, size_t ws_size,
                              hipStream_t stream) {
    const int*   tokens = (const int*)  d_in[0];
    const float* emb    = (const float*)d_in[1];
    const float* wk     = (const float*)d_in[2];
    const float* rk     = (const float*)d_in[3];
    const float* bias   = (const float*)d_in[4];
    const float* dw     = (const float*)d_in[5];
    const float* db     = (const float*)d_in[6];
    float* out = (float*)d_out;
    float* P   = (float*)d_ws;     // 20000*512*4 = 40.96 MB scratch

    proj_kernel<<<VV / 16, 512, 0, stream>>>(emb, wk, bias, P);
    lstm_kernel<<<BB, 512, 0, stream>>>(tokens, rk, P, dw, db, out);
}

// Round 14
// 302.635 us; speedup vs baseline: 1.2323x; 1.0017x over previous
//
#include <hip/hip_runtime.h>
#include <hip/hip_bf16.h>

// Problem constants: B,T,V,E,U = 256,512,20000,128,128
#define BB 256
#define TT 512
#define VV 20000
#define EE 128
#define UU 128
#define G4 512   // 4*U gate width

typedef _Float16 f16x8 __attribute__((ext_vector_type(8)));
typedef float    f32x4 __attribute__((ext_vector_type(4)));

__device__ __forceinline__ float sigmoid_f(float x) {
    float e = __expf(-x);
    return __builtin_amdgcn_rcpf(1.0f + e);
}
__device__ __forceinline__ float tanh_f(float x) {
    float e = __expf(2.0f * x);
    return 1.0f - 2.0f * __builtin_amdgcn_rcpf(e + 1.0f);
}

// ---------------------------------------------------------------------------
// Phase 1: projected-token table in GATE-MINOR layout:
//   P2[v][u][g] = sum_e emb[v][e]*K[e][g*128+u] + bias[g*128+u]
// (one float4 per (v,unit) = all 4 gates; coalesced store via tid->(g,u))
// ---------------------------------------------------------------------------
__global__ __launch_bounds__(512, 2) void proj_kernel(
    const float* __restrict__ emb, const float* __restrict__ wk,
    const float* __restrict__ bias, float* __restrict__ P2) {
    const int tid = threadIdx.x;
    const int g   = tid & 3;
    const int u   = tid >> 2;
    const int col = g * 128 + u;
    const int v0  = blockIdx.x * 16;

    __shared__ float elds[16 * EE];
    ((float4*)elds)[tid] = ((const float4*)(emb + (size_t)v0 * EE))[tid];
    __syncthreads();

    float bcol = bias[col];
    float acc[16];
#pragma unroll
    for (int r = 0; r < 16; ++r) acc[r] = bcol;

    const float4* elds4 = (const float4*)elds;
    for (int e0 = 0; e0 < EE; e0 += 4) {
        float k0 = wk[(e0 + 0) * G4 + col];
        float k1 = wk[(e0 + 1) * G4 + col];
        float k2 = wk[(e0 + 2) * G4 + col];
        float k3 = wk[(e0 + 3) * G4 + col];
#pragma unroll
        for (int r = 0; r < 16; ++r) {
            float4 ev = elds4[r * 32 + (e0 >> 2)];
            acc[r] = fmaf(ev.x, k0, acc[r]);
            acc[r] = fmaf(ev.y, k1, acc[r]);
            acc[r] = fmaf(ev.z, k2, acc[r]);
            acc[r] = fmaf(ev.w, k3, acc[r]);
        }
    }
#pragma unroll
    for (int r = 0; r < 16; ++r)
        P2[(size_t)(v0 + r) * G4 + tid] = acc[r];   // [v][u][g], coalesced
}

// ---------------------------------------------------------------------------
// Phase 2: sequential LSTM via MFMA — exact restoration of the measured-best
// structure (bench R7: 261 us lstm; MfmaUtil 44 / VALUBusy 47) with ONE
// change: per-gate interleaved source order. Gate g's z-extract/activation
// (VALU+trans) is independent of gate g+1's MFMA chain, so emitting
// MFMA(g) -> act(g) -> MFMA(g+1) -> ... exposes MFMA/VALU overlap the
// all-MFMAs-then-all-acts order forbids (pipes measured strictly serial).
//  * every lane holds z for all 4 gates of its unit (D-layout) -> no
//    cross-lane traffic; acts redundant x4 across kq groups (measured
//    cheaper than shfl exchange, R13 post-mortem).
//  * depth-4 static P prefetch (pf[4] float4, loop-carried SSA, counted
//    vmcnt); tokens in LDS padded +8 (no clamp); lgkmcnt(0)-only drain +
//    raw s_barrier (P loads cross the barrier).
// ---------------------------------------------------------------------------
__global__ __launch_bounds__(512, 2) void lstm_kernel(
    const int* __restrict__ tokens, const float* __restrict__ rk,
    const float* __restrict__ P2, const float* __restrict__ dense_w,
    const float* __restrict__ dense_b, float* __restrict__ out) {
    const int tid = threadIdx.x;
    const int w   = tid >> 6;       // wave 0..7
    const int l   = tid & 63;       // lane
    const int j   = l & 15;         // unit index within the wave's 16
    const int kq  = l >> 4;         // k-quarter (fragment row group)
    const int b   = blockIdx.x;
    const int ucol = 16 * w + j;    // unit column

    __shared__ __align__(16) _Float16 hbuf[2][UU];  // double-buffered h
    __shared__ int   tokLDS[TT + 8];                // padded token row
    __shared__ float red[8];

    // ---- B-fragments: bf[kt][g][i] = rk[32kt+8kq+i][g*128 + ucol] (f16) ----
    f16x8 bf[4][4];
#pragma unroll
    for (int kt = 0; kt < 4; ++kt) {
#pragma unroll
        for (int g = 0; g < 4; ++g) {
            f16x8 v;
#pragma unroll
            for (int i = 0; i < 8; ++i) {
                v[i] = (_Float16)rk[(size_t)(32 * kt + 8 * kq + i) * G4
                                    + g * 128 + ucol];
            }
            bf[kt][g] = v;
        }
    }

    const int* trow = tokens + (size_t)b * TT;
    tokLDS[tid] = trow[tid];
    if (tid < 8) tokLDS[TT + tid] = trow[TT - 1];   // pad: no clamp in loop
    if (tid < UU) hbuf[0][tid] = (_Float16)0.f;     // h0 = 0
    float c_state = 0.f, hv = 0.f;

    // this lane's P2 pointer: all 4 gates of unit ucol, 16B aligned
    const float4* Pc4 = (const float4*)(P2 + (size_t)ucol * 4);
    // depth-4 prologue: P for t = 0..3
    float4 pf[4];
#pragma unroll
    for (int s = 0; s < 4; ++s) pf[s] = Pc4[(size_t)trow[s] * 128];
    __syncthreads();

    const f32x4 cz = {0.f, 0.f, 0.f, 0.f};

    for (int t = 0; t < TT; t += 4) {
#pragma unroll
        for (int s = 0; s < 4; ++s) {
            // --- token for t+s+4 (LDS, padded) ---
            int vtok = tokLDS[t + s + 4];

            // --- A-fragments: h broadcast slices from LDS ---
            f16x8 af[4];
#pragma unroll
            for (int kt = 0; kt < 4; ++kt)
                af[kt] = *(const f16x8*)&hbuf[s & 1][32 * kt + 8 * kq];

            // --- issue P prefetch early (flies over the whole step) ---
            float4 pnew = Pc4[(size_t)vtok * 128];

            // === per-gate interleave: MFMA(g) then act(g) then MFMA(g+1) ===
            // gate 0 (i)
            f32x4 aA0 = __builtin_amdgcn_mfma_f32_16x16x32_f16(af[0], bf[0][0], cz, 0, 0, 0);
            f32x4 aB0 = __builtin_amdgcn_mfma_f32_16x16x32_f16(af[2], bf[2][0], cz, 0, 0, 0);
            aA0 = __builtin_amdgcn_mfma_f32_16x16x32_f16(af[1], bf[1][0], aA0, 0, 0, 0);
            aB0 = __builtin_amdgcn_mfma_f32_16x16x32_f16(af[3], bf[3][0], aB0, 0, 0, 0);
            float z0 = aA0[0] + aB0[0] + pf[s].x;
            float gi = sigmoid_f(z0);                 // overlaps gate-1 MFMAs

            // gate 1 (f)
            f32x4 aA1 = __builtin_amdgcn_mfma_f32_16x16x32_f16(af[0], bf[0][1], cz, 0, 0, 0);
            f32x4 aB1 = __builtin_amdgcn_mfma_f32_16x16x32_f16(af[2], bf[2][1], cz, 0, 0, 0);
            aA1 = __builtin_amdgcn_mfma_f32_16x16x32_f16(af[1], bf[1][1], aA1, 0, 0, 0);
            aB1 = __builtin_amdgcn_mfma_f32_16x16x32_f16(af[3], bf[3][1], aB1, 0, 0, 0);
            float z1 = aA1[0] + aB1[0] + pf[s].y;
            float gf = sigmoid_f(z1);

            // gate 2 (g) — tanh via sigmoid identity
            f32x4 aA2 = __builtin_amdgcn_mfma_f32_16x16x32_f16(af[0], bf[0][2], cz, 0, 0, 0);
            f32x4 aB2 = __builtin_amdgcn_mfma_f32_16x16x32_f16(af[2], bf[2][2], cz, 0, 0, 0);
            aA2 = __builtin_amdgcn_mfma_f32_16x16x32_f16(af[1], bf[1][2], aA2, 0, 0, 0);
            aB2 = __builtin_amdgcn_mfma_f32_16x16x32_f16(af[3], bf[3][2], aB2, 0, 0, 0);
            float z2 = aA2[0] + aB2[0] + pf[s].z;
            float gg = tanh_f(z2);

            // gate 3 (o)
            f32x4 aA3 = __builtin_amdgcn_mfma_f32_16x16x32_f16(af[0], bf[0][3], cz, 0, 0, 0);
            f32x4 aB3 = __builtin_amdgcn_mfma_f32_16x16x32_f16(af[2], bf[2][3], cz, 0, 0, 0);
            aA3 = __builtin_amdgcn_mfma_f32_16x16x32_f16(af[1], bf[1][3], aA3, 0, 0, 0);
            aB3 = __builtin_amdgcn_mfma_f32_16x16x32_f16(af[3], bf[3][3], aB3, 0, 0, 0);
            // c-update overlaps gate-3 MFMA chain
            c_state = fmaf(gf, c_state, gi * gg);
            float tc = tanh_f(c_state);
            float z3 = aA3[0] + aB3[0] + pf[s].w;
            float go = sigmoid_f(z3);
            hv = go * tc;

            if (kq == 0) hbuf[(s + 1) & 1][ucol] = (_Float16)hv;  // publish h
            pf[s] = pnew;

            // LDS-only drain + raw barrier: P loads survive across steps
            asm volatile("s_waitcnt lgkmcnt(0)" ::: "memory");
            __builtin_amdgcn_s_barrier();
        }
    }

    // --- dense sigmoid head: out[b] = sigmoid(h @ w + b) ---
    float val = (kq == 0) ? hv * dense_w[ucol] : 0.f;
#pragma unroll
    for (int off = 32; off > 0; off >>= 1) val += __shfl_xor(val, off, 64);
    if (l == 0) red[w] = val;
    __syncthreads();
    if (tid == 0) {
        float sum = dense_b[0];
#pragma unroll
        for (int i = 0; i < 8; ++i) sum += red[i];
        out[b] = sigmoid_f(sum);
    }
}

extern "C" void kernel_launch(void* const* d_in, const int* in_sizes, int n_in,
                              void* d_out, int out_size, void* d_ws, size_t ws_size,
                              hipStream_t stream) {
    const int*   tokens = (const int*)  d_in[0];
    const float* emb    = (const float*)d_in[1];
    const float* wk     = (const float*)d_in[2];
    const float* rk     = (const float*)d_in[3];
    const float* bias   = (const float*)d_in[4];
    const float* dw     = (const float*)d_in[5];
    const float* db     = (const float*)d_in[6];
    float* out = (float*)d_out;
    float* P2  = (float*)d_ws;     // 20000*512*4 = 40.96 MB scratch

    proj_kernel<<<VV / 16, 512, 0, stream>>>(emb, wk, bias, P2);
    lstm_kernel<<<BB, 512, 0, stream>>>(tokens, rk, P2, dw, db, out);
}